// Round 1
// 451.334 us; speedup vs baseline: 1.0567x; 1.0567x over previous
//
#include <hip/hip_runtime.h>
#include <cstdint>
#include <cstring>

// JAX PRNG variant: 1 = jax_threefry_partitionable=True (verified correct R1)
#define JAX_PARTITIONABLE 1

#define B_ 1024
#define P_ 512
#define K_ 128
#define MAXC 76
#define NSCORE 524288ull     // B*P
#define NRAND  67108864ull   // B*P*K
#define OFF_I  ((size_t)B_ * P_ * K_)          // 67108864
#define OFF_MT (OFF_I + (size_t)B_ * MAXC)     // + 77824

typedef float f4 __attribute__((ext_vector_type(4)));

// 2-bit mask_type codes for all 1024 rows, passed by value (256 B kernarg)
struct MTPack { uint32_t w[B_ / 16]; };

// ---------------- Threefry2x32 (exact JAX schedule) ----------------
__host__ __device__ inline uint32_t rotl32(uint32_t v, int d) {
    return (v << d) | (v >> (32 - d));
}

__host__ __device__ inline void tf2x32(uint32_t k0, uint32_t k1,
                                       uint32_t x0, uint32_t x1,
                                       uint32_t& o0, uint32_t& o1) {
    uint32_t ks2 = k0 ^ k1 ^ 0x1BD11BDAu;
    x0 += k0; x1 += k1;
#define TF_R(r) { x0 += x1; x1 = rotl32(x1, (r)); x1 ^= x0; }
    TF_R(13) TF_R(15) TF_R(26) TF_R(6)
    x0 += k1;  x1 += ks2 + 1u;
    TF_R(17) TF_R(29) TF_R(16) TF_R(24)
    x0 += ks2; x1 += k0 + 2u;
    TF_R(13) TF_R(15) TF_R(26) TF_R(6)
    x0 += k0;  x1 += k1 + 3u;
    TF_R(17) TF_R(29) TF_R(16) TF_R(24)
    x0 += k1;  x1 += ks2 + 4u;
    TF_R(13) TF_R(15) TF_R(26) TF_R(6)
    x0 += ks2; x1 += k0 + 5u;
#undef TF_R
    o0 = x0; o1 = x1;
}

__host__ __device__ inline uint32_t jax_bits(uint32_t k0, uint32_t k1,
                                             uint64_t i, uint64_t n) {
#if JAX_PARTITIONABLE
    (void)n;
    uint32_t o0, o1;
    tf2x32(k0, k1, (uint32_t)(i >> 32), (uint32_t)i, o0, o1);
    return o0 ^ o1;
#else
    uint64_t half = n >> 1;
    uint32_t o0, o1;
    if (i < half) { tf2x32(k0, k1, (uint32_t)i, (uint32_t)(i + half), o0, o1); return o0; }
    tf2x32(k0, k1, (uint32_t)(i - half), (uint32_t)i, o0, o1); return o1;
#endif
}

__device__ inline float u01(uint32_t bits) {
    return __uint_as_float((bits >> 9) | 0x3F800000u) - 1.0f;
}

// ---------------- Single fused kernel: selection + I + mt + x_out ----------
// T0 = mask_type[0] (compile-time specialized; host picks the instantiation)
template <int T0>
__global__ void __launch_bounds__(256) fused_kernel(const float* __restrict__ x,
                                                    const float* __restrict__ pos,
                                                    const float* __restrict__ wm,
                                                    const int* __restrict__ seq_len,
                                                    float* __restrict__ out,
                                                    float* __restrict__ I_out,
                                                    float* __restrict__ mt_out,
                                                    MTPack mtp,
                                                    uint32_t ks0, uint32_t ks1,
                                                    uint32_t kr0, uint32_t kr1) {
    int b = blockIdx.x;
    int tid = threadIdx.x;
    __shared__ float sc[P_];
    __shared__ uint32_t selmask[P_ / 32];

    int sl = seq_len[b];
    int n_valid = sl >> 3;
    int n_corr = (int)floorf(0.15f * (float)sl / 8.0f);   // f32, exactly as JAX

    if (tid < P_ / 32) selmask[tid] = 0u;

    // block 0 also emits mask_type (host-precomputed, 2 bits/row in kernarg)
    if (b == 0) {
        for (int j = tid; j < B_; j += 256)
            mt_out[j] = (float)((mtp.w[j >> 4] >> ((j & 15) * 2)) & 3u);
    }

    // pad I slots [n_corr, 76) with -1 (disjoint from rank-indexed writes)
    if (tid < MAXC && tid >= n_corr) I_out[(size_t)b * MAXC + tid] = -1.0f;

    if (n_corr > 0) {   // block-uniform branch (legal around __syncthreads)
        // scores for this row (2 per thread)
        for (int p = tid; p < P_; p += 256) {
            float s = __builtin_inff();
            if (p < n_valid) {
                uint32_t bits = jax_bits(ks0, ks1, (uint64_t)b * P_ + p, NSCORE);
                s = u01(bits);
            }
            sc[p] = s;
        }
        __syncthreads();

        // stable-sort ranks for both candidate patches in ONE pass over sc[]
        int p0 = tid, p1 = tid + 256;
        bool a0 = p0 < n_valid;
        bool a1 = p1 < n_valid;
        if (a0 | a1) {
            float s0 = sc[p0];
            float s1 = sc[p1];
            int r0 = 0, r1 = 0;
            for (int q = 0; q < n_valid; q++) {
                float sq = sc[q];
                r0 += (sq < s0) || (sq == s0 && q < p0);
                r1 += (sq < s1) || (sq == s1 && q < p1);
            }
            if (a0 && r0 < n_corr) {
                I_out[(size_t)b * MAXC + r0] = (float)p0;
                atomicOr(&selmask[p0 >> 5], 1u << (p0 & 31));
            }
            if (a1 && r1 < n_corr) {
                I_out[(size_t)b * MAXC + r1] = (float)p1;
                atomicOr(&selmask[p1 >> 5], 1u << (p1 & 31));
            }
        }
    }
    __syncthreads();

    // stream the row: 512*32 float4, single-touch -> nontemporal
    const f4* x4  = (const f4*)x + (size_t)b * (P_ * (K_ / 4));
    f4*       o4  = (f4*)out     + (size_t)b * (P_ * (K_ / 4));
    const f4* p4  = (const f4*)pos;                    // reused 1024x -> cached
    const f4* wm4 = (const f4*)wm;

    for (int i = tid; i < P_ * (K_ / 4); i += 256) {
        f4 v;
        if (T0 == 2) {
            // replacement == x : pure copy
            v = __builtin_nontemporal_load(&x4[i]);
        } else {
            int p  = i >> 5;       // patch
            bool sel = (selmask[p >> 5] >> (p & 31)) & 1u;
            if (!sel) {
                v = __builtin_nontemporal_load(&x4[i]);
            } else {
                int kq = i & 31;   // float4 within patch
                f4 c = p4[p * (K_ / 4) + kq];
                if (T0 == 0) {
                    v = wm4[kq] + c;
                } else { // T0 == 1
                    uint64_t e = (((uint64_t)b * P_ + p) * K_) + (uint64_t)kq * 4;
                    v.x = u01(jax_bits(kr0, kr1, e + 0, NRAND)) + c.x;
                    v.y = u01(jax_bits(kr0, kr1, e + 1, NRAND)) + c.y;
                    v.z = u01(jax_bits(kr0, kr1, e + 2, NRAND)) + c.z;
                    v.w = u01(jax_bits(kr0, kr1, e + 3, NRAND)) + c.w;
                }
            }
        }
        __builtin_nontemporal_store(v, &o4[i]);
    }
}

// ---------------- Host ----------------
extern "C" void kernel_launch(void* const* d_in, const int* in_sizes, int n_in,
                              void* d_out, int out_size, void* d_ws, size_t ws_size,
                              hipStream_t stream) {
    (void)in_sizes; (void)n_in; (void)d_ws; (void)ws_size; (void)out_size;
    const float* x   = (const float*)d_in[0];
    const float* pos = (const float*)d_in[1];
    const float* wm  = (const float*)d_in[2];
    const int* seq_len = (const int*)d_in[3];
    float* out = (float*)d_out;

    // Seed-only precompute: derived keys + all 1024 mask_type codes + t0.
    static bool init_done = false;
    static MTPack mtp;
    static int t0 = 0;
    static uint32_t ks0, ks1, kr0, kr1;
    if (!init_done) {
        uint32_t kp0, kp1, sub0, sub1;
#if JAX_PARTITIONABLE
        tf2x32(0u, 42u, 0u, 0u, kp0, kp1);
        tf2x32(0u, 42u, 0u, 1u, ks0, ks1);
        tf2x32(0u, 42u, 0u, 2u, kr0, kr1);
        tf2x32(kp0, kp1, 0u, 1u, sub0, sub1);   // split(kp,2)[1]
#else
        {
            uint32_t a0, b0, a1, b1, a2, b2;
            tf2x32(0u, 42u, 0u, 3u, a0, b0);
            tf2x32(0u, 42u, 1u, 4u, a1, b1);
            tf2x32(0u, 42u, 2u, 5u, a2, b2);
            kp0 = a0; kp1 = a1; ks0 = a2; ks1 = b0; kr0 = b1; kr1 = b2;
            uint32_t c0, d0, c1, d1;
            tf2x32(kp0, kp1, 0u, 2u, c0, d0);
            tf2x32(kp0, kp1, 1u, 3u, c1, d1);
            sub0 = d0; sub1 = d1;
        }
#endif
        static uint32_t skeys[B_];
        for (int i = 0; i < B_; i++)
            skeys[i] = jax_bits(sub0, sub1, (uint64_t)i, (uint64_t)B_);
        memset(&mtp, 0, sizeof(mtp));
        for (int i = 0; i < B_; i++) {
            uint32_t ki = skeys[i];
            int rank = 0;
            for (int q = 0; q < B_; q++) {
                uint32_t kq = skeys[q];
                rank += (kq < ki) || (kq == ki && q < i);
            }
            uint32_t code = rank < 819 ? 0u : (rank < 921 ? 1u : 2u);
            mtp.w[i >> 4] |= code << ((i & 15) * 2);
        }
        t0 = (int)(mtp.w[0] & 3u);
        init_done = true;
    }

    float* I_out  = out + OFF_I;
    float* mt_out = out + OFF_MT;

    switch (t0) {
    case 0:
        fused_kernel<0><<<dim3(B_), dim3(256), 0, stream>>>(
            x, pos, wm, seq_len, out, I_out, mt_out, mtp, ks0, ks1, kr0, kr1);
        break;
    case 1:
        fused_kernel<1><<<dim3(B_), dim3(256), 0, stream>>>(
            x, pos, wm, seq_len, out, I_out, mt_out, mtp, ks0, ks1, kr0, kr1);
        break;
    default:
        fused_kernel<2><<<dim3(B_), dim3(256), 0, stream>>>(
            x, pos, wm, seq_len, out, I_out, mt_out, mtp, ks0, ks1, kr0, kr1);
        break;
    }
}

// Round 2
// 442.992 us; speedup vs baseline: 1.0766x; 1.0188x over previous
//
#include <hip/hip_runtime.h>
#include <cstdint>
#include <cstring>

// JAX PRNG variant: 1 = jax_threefry_partitionable=True (verified correct R1)
#define JAX_PARTITIONABLE 1

#define B_ 1024
#define P_ 512
#define K_ 128
#define MAXC 76
#define NSCORE 524288ull     // B*P
#define NRAND  67108864ull   // B*P*K
#define OFF_I  ((size_t)B_ * P_ * K_)          // 67108864
#define OFF_MT (OFF_I + (size_t)B_ * MAXC)     // + 77824

typedef float f4 __attribute__((ext_vector_type(4)));

// 2-bit mask_type codes for all 1024 rows, passed by value (256 B kernarg)
struct MTPack { uint32_t w[B_ / 16]; };

// ---------------- Threefry2x32 (exact JAX schedule) ----------------
__host__ __device__ inline uint32_t rotl32(uint32_t v, int d) {
    return (v << d) | (v >> (32 - d));
}

__host__ __device__ inline void tf2x32(uint32_t k0, uint32_t k1,
                                       uint32_t x0, uint32_t x1,
                                       uint32_t& o0, uint32_t& o1) {
    uint32_t ks2 = k0 ^ k1 ^ 0x1BD11BDAu;
    x0 += k0; x1 += k1;
#define TF_R(r) { x0 += x1; x1 = rotl32(x1, (r)); x1 ^= x0; }
    TF_R(13) TF_R(15) TF_R(26) TF_R(6)
    x0 += k1;  x1 += ks2 + 1u;
    TF_R(17) TF_R(29) TF_R(16) TF_R(24)
    x0 += ks2; x1 += k0 + 2u;
    TF_R(13) TF_R(15) TF_R(26) TF_R(6)
    x0 += k0;  x1 += k1 + 3u;
    TF_R(17) TF_R(29) TF_R(16) TF_R(24)
    x0 += k1;  x1 += ks2 + 4u;
    TF_R(13) TF_R(15) TF_R(26) TF_R(6)
    x0 += ks2; x1 += k0 + 5u;
#undef TF_R
    o0 = x0; o1 = x1;
}

__host__ __device__ inline uint32_t jax_bits(uint32_t k0, uint32_t k1,
                                             uint64_t i, uint64_t n) {
#if JAX_PARTITIONABLE
    (void)n;
    uint32_t o0, o1;
    tf2x32(k0, k1, (uint32_t)(i >> 32), (uint32_t)i, o0, o1);
    return o0 ^ o1;
#else
    uint64_t half = n >> 1;
    uint32_t o0, o1;
    if (i < half) { tf2x32(k0, k1, (uint32_t)i, (uint32_t)(i + half), o0, o1); return o0; }
    tf2x32(k0, k1, (uint32_t)(i - half), (uint32_t)i, o0, o1); return o1;
#endif
}

__device__ inline float u01(uint32_t bits) {
    return __uint_as_float((bits >> 9) | 0x3F800000u) - 1.0f;
}

// ---------------- Single fused kernel: selection + I + mt + x_out ----------
// T0 = mask_type[0] (compile-time specialized; host picks the instantiation)
// Block = 512 threads (8 waves); 1024 blocks -> 4 blocks/CU = 32 waves/CU max
// occupancy. T0 in {0,2}: force 8 waves/EU (needs <=64 VGPR -- stream path is
// load/blend/store only). T0==1 keeps threefry in the stream loop -> 4 waves/EU.
template <int T0>
__global__ void __launch_bounds__(512, (T0 == 1 ? 4 : 8))
fused_kernel(const float* __restrict__ x,
             const float* __restrict__ pos,
             const float* __restrict__ wm,
             const int* __restrict__ seq_len,
             float* __restrict__ out,
             float* __restrict__ I_out,
             float* __restrict__ mt_out,
             MTPack mtp,
             uint32_t ks0, uint32_t ks1,
             uint32_t kr0, uint32_t kr1) {
    int b = blockIdx.x;
    int tid = threadIdx.x;
    __shared__ float sc[P_];
    __shared__ uint32_t selmask[P_ / 32];

    int sl = seq_len[b];
    int n_valid = sl >> 3;
    int n_corr = (int)floorf(0.15f * (float)sl / 8.0f);   // f32, exactly as JAX

    if (tid < P_ / 32) selmask[tid] = 0u;

    // block 0 also emits mask_type (host-precomputed, 2 bits/row in kernarg)
    if (b == 0) {
        for (int j = tid; j < B_; j += 512)
            mt_out[j] = (float)((mtp.w[j >> 4] >> ((j & 15) * 2)) & 3u);
    }

    // pad I slots [n_corr, 76) with -1 (disjoint from rank-indexed writes)
    if (tid < MAXC && tid >= n_corr) I_out[(size_t)b * MAXC + tid] = -1.0f;

    if (n_corr > 0) {   // block-uniform branch (legal around __syncthreads)
        // one score per thread; invalid patches padded with +inf
        {
            float s = __builtin_inff();
            if (tid < n_valid) {
                uint32_t bits = jax_bits(ks0, ks1, (uint64_t)b * P_ + tid, NSCORE);
                s = u01(bits);
            }
            sc[tid] = s;
        }
        __syncthreads();

        // stable-sort rank, one patch per thread, f4-vectorized LDS reads.
        // Ragged tail is handled by the +inf padding (inf never increments rank).
        if (tid < n_valid) {
            float sp = sc[tid];
            int rank = 0;
            const f4* sc4 = (const f4*)sc;
            int nq4 = (n_valid + 3) >> 2;
            for (int q4 = 0; q4 < nq4; q4++) {
                f4 s4 = sc4[q4];
                int qb = q4 << 2;
                rank += (s4.x < sp) || (s4.x == sp && qb + 0 < tid);
                rank += (s4.y < sp) || (s4.y == sp && qb + 1 < tid);
                rank += (s4.z < sp) || (s4.z == sp && qb + 2 < tid);
                rank += (s4.w < sp) || (s4.w == sp && qb + 3 < tid);
            }
            if (rank < n_corr) {
                I_out[(size_t)b * MAXC + rank] = (float)tid;
                atomicOr(&selmask[tid >> 5], 1u << (tid & 31));
            }
        }
    }
    __syncthreads();

    // stream the row: 16384 float4, 32 per thread, unroll x4 for MLP.
    // Loads are unconditional (branch-free issue); blend is exec-masked.
    const f4* x4  = (const f4*)x + (size_t)b * (P_ * (K_ / 4));
    f4*       o4  = (f4*)out     + (size_t)b * (P_ * (K_ / 4));
    const f4* p4  = (const f4*)pos;                    // reused 1024x -> cached
    const f4* wm4 = (const f4*)wm;

    if (T0 == 2) {
        // replacement == x : pure copy, no sel needed
        for (int k = 0; k < 32; k += 4) {
            f4 v[4];
#pragma unroll
            for (int u = 0; u < 4; u++)
                v[u] = __builtin_nontemporal_load(&x4[tid + (k + u) * 512]);
#pragma unroll
            for (int u = 0; u < 4; u++)
                __builtin_nontemporal_store(v[u], &o4[tid + (k + u) * 512]);
        }
    } else {
        const int kq = tid & 31;    // float4 within patch (constant per lane)
        const int pb = tid >> 5;    // base patch (0..15)
        f4 wmv;
        if (T0 == 0) wmv = wm4[kq];
        for (int k = 0; k < 32; k += 4) {
            f4 v[4];
#pragma unroll
            for (int u = 0; u < 4; u++)
                v[u] = __builtin_nontemporal_load(&x4[tid + (k + u) * 512]);
#pragma unroll
            for (int u = 0; u < 4; u++) {
                int pp = pb + (k + u) * 16;
                bool sel = (selmask[pp >> 5] >> (pp & 31)) & 1u;
                if (sel) {
                    f4 c = p4[pp * (K_ / 4) + kq];
                    if (T0 == 0) {
                        v[u] = wmv + c;
                    } else { // T0 == 1
                        uint64_t e = (((uint64_t)b * P_ + pp) * K_) + (uint64_t)kq * 4;
                        v[u].x = u01(jax_bits(kr0, kr1, e + 0, NRAND)) + c.x;
                        v[u].y = u01(jax_bits(kr0, kr1, e + 1, NRAND)) + c.y;
                        v[u].z = u01(jax_bits(kr0, kr1, e + 2, NRAND)) + c.z;
                        v[u].w = u01(jax_bits(kr0, kr1, e + 3, NRAND)) + c.w;
                    }
                }
            }
#pragma unroll
            for (int u = 0; u < 4; u++)
                __builtin_nontemporal_store(v[u], &o4[tid + (k + u) * 512]);
        }
    }
}

// ---------------- Host ----------------
extern "C" void kernel_launch(void* const* d_in, const int* in_sizes, int n_in,
                              void* d_out, int out_size, void* d_ws, size_t ws_size,
                              hipStream_t stream) {
    (void)in_sizes; (void)n_in; (void)d_ws; (void)ws_size; (void)out_size;
    const float* x   = (const float*)d_in[0];
    const float* pos = (const float*)d_in[1];
    const float* wm  = (const float*)d_in[2];
    const int* seq_len = (const int*)d_in[3];
    float* out = (float*)d_out;

    // Seed-only precompute: derived keys + all 1024 mask_type codes + t0.
    static bool init_done = false;
    static MTPack mtp;
    static int t0 = 0;
    static uint32_t ks0, ks1, kr0, kr1;
    if (!init_done) {
        uint32_t kp0, kp1, sub0, sub1;
#if JAX_PARTITIONABLE
        tf2x32(0u, 42u, 0u, 0u, kp0, kp1);
        tf2x32(0u, 42u, 0u, 1u, ks0, ks1);
        tf2x32(0u, 42u, 0u, 2u, kr0, kr1);
        tf2x32(kp0, kp1, 0u, 1u, sub0, sub1);   // split(kp,2)[1]
#else
        {
            uint32_t a0, b0, a1, b1, a2, b2;
            tf2x32(0u, 42u, 0u, 3u, a0, b0);
            tf2x32(0u, 42u, 1u, 4u, a1, b1);
            tf2x32(0u, 42u, 2u, 5u, a2, b2);
            kp0 = a0; kp1 = a1; ks0 = a2; ks1 = b0; kr0 = b1; kr1 = b2;
            uint32_t c0, d0, c1, d1;
            tf2x32(kp0, kp1, 0u, 2u, c0, d0);
            tf2x32(kp0, kp1, 1u, 3u, c1, d1);
            sub0 = d0; sub1 = d1;
        }
#endif
        static uint32_t skeys[B_];
        for (int i = 0; i < B_; i++)
            skeys[i] = jax_bits(sub0, sub1, (uint64_t)i, (uint64_t)B_);
        memset(&mtp, 0, sizeof(mtp));
        for (int i = 0; i < B_; i++) {
            uint32_t ki = skeys[i];
            int rank = 0;
            for (int q = 0; q < B_; q++) {
                uint32_t kq = skeys[q];
                rank += (kq < ki) || (kq == ki && q < i);
            }
            uint32_t code = rank < 819 ? 0u : (rank < 921 ? 1u : 2u);
            mtp.w[i >> 4] |= code << ((i & 15) * 2);
        }
        t0 = (int)(mtp.w[0] & 3u);
        init_done = true;
    }

    float* I_out  = out + OFF_I;
    float* mt_out = out + OFF_MT;

    switch (t0) {
    case 0:
        fused_kernel<0><<<dim3(B_), dim3(512), 0, stream>>>(
            x, pos, wm, seq_len, out, I_out, mt_out, mtp, ks0, ks1, kr0, kr1);
        break;
    case 1:
        fused_kernel<1><<<dim3(B_), dim3(512), 0, stream>>>(
            x, pos, wm, seq_len, out, I_out, mt_out, mtp, ks0, ks1, kr0, kr1);
        break;
    default:
        fused_kernel<2><<<dim3(B_), dim3(512), 0, stream>>>(
            x, pos, wm, seq_len, out, I_out, mt_out, mtp, ks0, ks1, kr0, kr1);
        break;
    }
}